// Round 1
// baseline (548.758 us; speedup 1.0000x reference)
//
#include <hip/hip_runtime.h>
#include <hip/hip_bf16.h>

#define B_ 4
#define L_ 4096
#define D_ 1024
#define N_ 64
#define K_ 4

__device__ __forceinline__ float softplus_f(float x) {
    // log(1+exp(x)) = max(x,0) + log1p(exp(-|x|))
    return fmaxf(x, 0.0f) + log1pf(__expf(-fabsf(x)));
}

__device__ __forceinline__ float tanh_f(float x) {
    float xc = fminf(fmaxf(x, -15.0f), 15.0f);
    float e = __expf(2.0f * xc);
    return (e - 1.0f) / (e + 1.0f);
}

// ---------------------------------------------------------------------------
// Kernel 1: fused causal depthwise conv + proj GEMM (D x 128) + u GEMM (D x 64)
// Block: 192 threads (3 waves), tile = 32 tokens x 192 output cols, BK = 32.
// Epilogue: z = dt * softplus(projB) * u ; Ct = tanh(projC), written transposed
// to zT/CT [B][N][L] for contiguous scan access.
// ---------------------------------------------------------------------------
#define TM 32
#define BK 32
#define NTH1 192

__global__ __launch_bounds__(NTH1) void k_frontend(
    const float* __restrict__ x, const float* __restrict__ conv_w,
    const float* __restrict__ conv_b, const float* __restrict__ Wp,
    const float* __restrict__ bp, const float* __restrict__ Ws,
    const float* __restrict__ bs, const float* __restrict__ A_log,
    const float* __restrict__ dt_log,
    float* __restrict__ zT, float* __restrict__ CT)
{
    // halo x tile: [kk][ti], ti = 0..34 (tokens t0-3 .. t0+31), stride 37
    __shared__ float xh[BK * 37];
    // operand tiles: [0] = conv (tokens t0..t0+31), [1] = raw x ; stride 36 (16B aligned)
    __shared__ float opA[2 * BK * 36];
    __shared__ float Wps[BK * 128];
    __shared__ float Wss[BK * 64];
    __shared__ float wcs[K_ * BK];
    __shared__ float proj_s[TM * 130];
    __shared__ float u_s[TM * 66];

    const int tid = threadIdx.x;
    const int tx = tid % 24;        // 24 col-groups of 8
    const int ty = tid / 24;        // 8 token-groups of 4
    const int bx = blockIdx.x;
    const int b  = bx >> 7;         // 128 token tiles per batch
    const int t0 = (bx & 127) * TM;

    const bool isProj = (tx < 16);
    const int colBase = isProj ? tx * 8 : (tx - 16) * 8;

    float acc[4][8];
    #pragma unroll
    for (int i = 0; i < 4; i++)
        #pragma unroll
        for (int j = 0; j < 8; j++) acc[i][j] = 0.0f;

    const float* aBase = isProj ? &opA[0] : &opA[BK * 36];
    const float* wBase = isProj ? &Wps[colBase] : &Wss[colBase];
    const int wstr = isProj ? 128 : 64;

    for (int d0 = 0; d0 < D_; d0 += BK) {
        __syncthreads();
        // stage halo x tile (35 rows x BK cols), transposed into LDS
        for (int idx = tid; idx < 35 * BK; idx += NTH1) {
            int ti = idx >> 5, kk = idx & 31;
            int t = t0 + ti - 3;
            float v = 0.0f;
            if (t >= 0) v = x[((size_t)b * L_ + t) * D_ + d0 + kk];
            xh[kk * 37 + ti] = v;
        }
        // stage Wp chunk (contiguous) and Ws chunk (contiguous)
        for (int idx = tid; idx < BK * 128; idx += NTH1)
            Wps[idx] = Wp[d0 * 128 + idx];
        for (int idx = tid; idx < BK * 64; idx += NTH1)
            Wss[idx] = Ws[d0 * 64 + idx];
        // conv weights chunk
        for (int idx = tid; idx < K_ * BK; idx += NTH1) {
            int k = idx >> 5, kk = idx & 31;
            wcs[idx] = conv_w[k * D_ + d0 + kk];
        }
        __syncthreads();
        // build conv tile + aligned raw-x tile
        for (int idx = tid; idx < BK * TM; idx += NTH1) {
            int kk = idx >> 5, tl = idx & 31;
            const float* xr = &xh[kk * 37 + tl];
            float c = conv_b[d0 + kk];
            c = fmaf(xr[0], wcs[0 * BK + kk], c);
            c = fmaf(xr[1], wcs[1 * BK + kk], c);
            c = fmaf(xr[2], wcs[2 * BK + kk], c);
            c = fmaf(xr[3], wcs[3 * BK + kk], c);
            opA[kk * 36 + tl] = c;          // conv for token t0+tl
            opA[BK * 36 + kk * 36 + tl] = xr[3];  // raw x for token t0+tl
        }
        __syncthreads();
        // main FMA loop
        #pragma unroll 4
        for (int kk = 0; kk < BK; kk++) {
            const float4 a  = *(const float4*)(aBase + kk * 36 + ty * 4);
            const float4 w0 = *(const float4*)(wBase + kk * wstr);
            const float4 w1 = *(const float4*)(wBase + kk * wstr + 4);
            float av[4] = {a.x, a.y, a.z, a.w};
            float wv[8] = {w0.x, w0.y, w0.z, w0.w, w1.x, w1.y, w1.z, w1.w};
            #pragma unroll
            for (int i = 0; i < 4; i++)
                #pragma unroll
                for (int j = 0; j < 8; j++)
                    acc[i][j] = fmaf(av[i], wv[j], acc[i][j]);
        }
    }

    __syncthreads();
    // write accumulators (+ bias) to LDS for cross-thread combine
    #pragma unroll
    for (int i = 0; i < 4; i++) {
        int tl = ty * 4 + i;
        #pragma unroll
        for (int j = 0; j < 8; j++) {
            int c = colBase + j;
            if (isProj) proj_s[tl * 130 + c] = acc[i][j] + bp[c];
            else        u_s[tl * 66 + c]    = acc[i][j] + bs[c];
        }
    }
    __syncthreads();
    // combine: z = dt * softplus(projB) * u ; Ct = tanh(projC); transposed store
    for (int idx = tid; idx < TM * N_; idx += NTH1) {
        int n = idx >> 5, tl = idx & 31;
        float pb = proj_s[tl * 130 + n];
        float pc = proj_s[tl * 130 + 64 + n];
        float uu = u_s[tl * 66 + n];
        float dtv = softplus_f(dt_log[n]);
        float bt = softplus_f(pb);
        float ct = tanh_f(pc);
        float z = dtv * bt * uu;
        size_t o = ((size_t)(b * N_ + n)) * L_ + t0 + tl;
        zT[o] = z;
        CT[o] = ct;
    }
}

// ---------------------------------------------------------------------------
// Kernel 2: parallel linear scan. One block (64 threads) per (b,n) chain.
// state_l = decay*state_{l-1} + z_l ; y_l = C_l * state_l
// Each lane scans a 64-step chunk locally; chunk carries stitched exactly via
// wave-level affine-composition scan (f(x) = decay^64 * x + e_chunk).
// ---------------------------------------------------------------------------
__global__ __launch_bounds__(64) void k_scan(
    const float* __restrict__ zT, const float* __restrict__ CT,
    const float* __restrict__ A_log, const float* __restrict__ dt_log,
    float* __restrict__ yT)
{
    __shared__ float zs[L_];
    __shared__ float cs[L_];
    const int bn = blockIdx.x;      // b*64 + n
    const int n = bn & (N_ - 1);
    const int lane = threadIdx.x;
    const float* zp = zT + (size_t)bn * L_;
    const float* cp = CT + (size_t)bn * L_;

    for (int i = lane * 4; i < L_; i += 64 * 4) {
        *(float4*)&zs[i] = *(const float4*)&zp[i];
        *(float4*)&cs[i] = *(const float4*)&cp[i];
    }
    __syncthreads();

    float dtv = softplus_f(dt_log[n]);
    float Av = -softplus_f(A_log[n]);
    float dec = fmaf(dtv, Av, 1.0f);

    // local (zero-init) chunk scan
    float s = 0.0f;
    const int base = lane * 64;
    #pragma unroll
    for (int j = 0; j < 64; j++) s = fmaf(dec, s, zs[base + j]);

    // decay^64 by repeated squaring
    float d2 = dec * dec, d4 = d2 * d2, d8 = d4 * d4;
    float d16 = d8 * d8, d32 = d16 * d16, d64 = d32 * d32;

    // inclusive affine scan across lanes: F = f_lane o F_prev
    float Ag = d64, Bg = s;
    #pragma unroll
    for (int off = 1; off < 64; off <<= 1) {
        float Ap = __shfl_up(Ag, off);
        float Bp = __shfl_up(Bg, off);
        if (lane >= off) { Bg = fmaf(Ag, Bp, Bg); Ag *= Ap; }
    }
    float carry = __shfl_up(Bg, 1);
    if (lane == 0) carry = 0.0f;

    // replay with true carry-in; overwrite zs with y = C * state
    float st = carry;
    #pragma unroll
    for (int j = 0; j < 64; j++) {
        st = fmaf(dec, st, zs[base + j]);
        zs[base + j] = cs[base + j] * st;
    }
    __syncthreads();
    float* yp = yT + (size_t)bn * L_;
    for (int i = lane * 4; i < L_; i += 64 * 4)
        *(float4*)&yp[i] = *(const float4*)&zs[i];
}

// ---------------------------------------------------------------------------
// Kernel 3: out = y @ Wo + bo.  Tile 64 tokens x 128 dims, K = N = 64.
// yT is [B][N][L] so the A-operand loads are contiguous along l.
// ---------------------------------------------------------------------------
#define TL3 64
#define TD3 128

__global__ __launch_bounds__(256) void k_out(
    const float* __restrict__ yT, const float* __restrict__ Wo,
    const float* __restrict__ bo, float* __restrict__ out)
{
    __shared__ float ysv[N_ * 68];      // [n][l], stride 68 (16B aligned)
    __shared__ float wos[N_ * TD3];     // [n][d]
    const int tid = threadIdx.x;
    const int tx = tid & 15;            // 8 d-cols each
    const int ty = tid >> 4;            // 4 l-rows each
    const int d0 = blockIdx.x * TD3;
    const int l0 = blockIdx.y * TL3;
    const int b  = blockIdx.z;

    for (int idx = tid; idx < N_ * TL3; idx += 256) {
        int nn = idx >> 6, li = idx & 63;
        ysv[nn * 68 + li] = yT[((size_t)(b * N_ + nn)) * L_ + l0 + li];
    }
    for (int idx = tid; idx < N_ * TD3; idx += 256) {
        int nn = idx >> 7, dd = idx & 127;
        wos[idx] = Wo[nn * D_ + d0 + dd];
    }
    __syncthreads();

    float acc[4][8];
    #pragma unroll
    for (int i = 0; i < 4; i++)
        #pragma unroll
        for (int j = 0; j < 8; j++) acc[i][j] = 0.0f;

    #pragma unroll 8
    for (int nn = 0; nn < N_; nn++) {
        const float4 a  = *(const float4*)(&ysv[nn * 68 + ty * 4]);
        const float4 w0 = *(const float4*)(&wos[nn * 128 + tx * 8]);
        const float4 w1 = *(const float4*)(&wos[nn * 128 + tx * 8 + 4]);
        float av[4] = {a.x, a.y, a.z, a.w};
        float wv[8] = {w0.x, w0.y, w0.z, w0.w, w1.x, w1.y, w1.z, w1.w};
        #pragma unroll
        for (int i = 0; i < 4; i++)
            #pragma unroll
            for (int j = 0; j < 8; j++)
                acc[i][j] = fmaf(av[i], wv[j], acc[i][j]);
    }

    const float4 b0 = *(const float4*)(bo + d0 + tx * 8);
    const float4 b1 = *(const float4*)(bo + d0 + tx * 8 + 4);
    #pragma unroll
    for (int i = 0; i < 4; i++) {
        size_t o = ((size_t)b * L_ + l0 + ty * 4 + i) * D_ + d0 + tx * 8;
        float4 o0 = {acc[i][0] + b0.x, acc[i][1] + b0.y,
                     acc[i][2] + b0.z, acc[i][3] + b0.w};
        float4 o1 = {acc[i][4] + b1.x, acc[i][5] + b1.y,
                     acc[i][6] + b1.z, acc[i][7] + b1.w};
        *(float4*)(out + o) = o0;
        *(float4*)(out + o + 4) = o1;
    }
}

// ---------------------------------------------------------------------------
extern "C" void kernel_launch(void* const* d_in, const int* in_sizes, int n_in,
                              void* d_out, int out_size, void* d_ws, size_t ws_size,
                              hipStream_t stream) {
    const float* x      = (const float*)d_in[0];
    const float* conv_w = (const float*)d_in[1];
    const float* conv_b = (const float*)d_in[2];
    const float* Wp     = (const float*)d_in[3];
    const float* bp     = (const float*)d_in[4];
    const float* Ws     = (const float*)d_in[5];
    const float* bs     = (const float*)d_in[6];
    const float* A_log  = (const float*)d_in[7];
    const float* dt_log = (const float*)d_in[8];
    const float* Wo     = (const float*)d_in[9];
    const float* bo     = (const float*)d_in[10];
    float* out = (float*)d_out;

    const size_t chainElems = (size_t)B_ * N_ * L_;   // 1,048,576
    float* zT = (float*)d_ws;
    float* CT = zT + chainElems;
    float* yT = CT + chainElems;

    k_frontend<<<dim3(B_ * (L_ / TM)), dim3(NTH1), 0, stream>>>(
        x, conv_w, conv_b, Wp, bp, Ws, bs, A_log, dt_log, zT, CT);
    k_scan<<<dim3(B_ * N_), dim3(64), 0, stream>>>(zT, CT, A_log, dt_log, yT);
    k_out<<<dim3(D_ / TD3, L_ / TL3, B_), dim3(256), 0, stream>>>(yT, Wo, bo, out);
}

// Round 2
// 404.052 us; speedup vs baseline: 1.3581x; 1.3581x over previous
//
#include <hip/hip_runtime.h>
#include <hip/hip_fp16.h>

#define B_ 4
#define L_ 4096
#define D_ 1024
#define N_ 64
#define K_ 4

__device__ __forceinline__ float softplus_f(float x) {
    return fmaxf(x, 0.0f) + log1pf(__expf(-fabsf(x)));
}

__device__ __forceinline__ float tanh_f(float x) {
    float xc = fminf(fmaxf(x, -15.0f), 15.0f);
    float e = __expf(2.0f * xc);
    return (e - 1.0f) / (e + 1.0f);
}

__device__ __forceinline__ void store_h4(__half* dst, float a, float b, float c, float d) {
    __half2 lo = __floats2half2_rn(a, b);
    __half2 hi = __floats2half2_rn(c, d);
    uint2 u;
    u.x = *(const unsigned int*)&lo;
    u.y = *(const unsigned int*)&hi;
    *(uint2*)dst = u;
}

// ---------------------------------------------------------------------------
// Kernel 1: frontend GEMMs. grid (512, 2): blockIdx.y==0 -> proj block
// (32 tokens x 128 cols of conv(x) @ Wp, then softplus/tanh, fp16 out);
// blockIdx.y==1 -> u block (32 tokens x 64 cols of x @ Ws, fp16 out).
// 128 threads, BK=32, conflict-free LDS: all float4 LDS accesses are
// lane-consecutive (16B stride across lanes).
// ---------------------------------------------------------------------------
#define NTF 128

__global__ __launch_bounds__(NTF) void k_frontend(
    const float* __restrict__ x, const float* __restrict__ conv_w,
    const float* __restrict__ conv_b, const float* __restrict__ Wp,
    const float* __restrict__ bp, const float* __restrict__ Ws,
    const float* __restrict__ bs,
    __half* __restrict__ projA, __half* __restrict__ uA)
{
    __shared__ float xh[32 * 40];     // [kk][ti], ti 0..35 = tokens t0-4..t0+31
    __shared__ float convs[32 * 36];  // [kk][tl], tl 0..31 (proj blocks only)
    __shared__ float wls[32 * 128];   // weight chunk (proj: 128 cols; u: 64)
    __shared__ float wcs[4 * 32];
    __shared__ float cbs[32];

    const int tid = threadIdx.x;
    const int tx = tid & 15;          // col group
    const int ty = tid >> 4;          // token group (0..7), 4 tokens each
    const int bx = blockIdx.x;
    const bool isU = (blockIdx.y != 0);
    const int b  = bx >> 7;
    const int t0 = (bx & 127) * 32;
    const size_t rowBase = (size_t)b * L_ + t0;

    if (!isU) {
        float acc[4][8];
        #pragma unroll
        for (int i = 0; i < 4; i++)
            #pragma unroll
            for (int j = 0; j < 8; j++) acc[i][j] = 0.0f;

        for (int d0 = 0; d0 < D_; d0 += 32) {
            __syncthreads();
            // stage x halo tile (36 tokens x 32 dims), transposed
            for (int idx = tid; idx < 288; idx += NTF) {
                int ti = idx >> 3, k4 = idx & 7;
                int t = t0 + ti - 4;
                float4 v = make_float4(0.f, 0.f, 0.f, 0.f);
                if (t >= 0)
                    v = *(const float4*)&x[((size_t)b * L_ + t) * D_ + d0 + k4 * 4];
                xh[(k4 * 4 + 0) * 40 + ti] = v.x;
                xh[(k4 * 4 + 1) * 40 + ti] = v.y;
                xh[(k4 * 4 + 2) * 40 + ti] = v.z;
                xh[(k4 * 4 + 3) * 40 + ti] = v.w;
            }
            // stage Wp chunk [32][128]
            for (int idx = tid; idx < 1024; idx += NTF) {
                int kk = idx >> 5, c4 = idx & 31;
                *(float4*)&wls[kk * 128 + c4 * 4] =
                    *(const float4*)&Wp[(size_t)(d0 + kk) * 128 + c4 * 4];
            }
            wcs[tid] = conv_w[(tid >> 5) * D_ + d0 + (tid & 31)];
            if (tid < 32) cbs[tid] = conv_b[d0 + tid];
            __syncthreads();
            // build conv tile [32 kk][32 tl]
            for (int idx = tid; idx < 1024; idx += NTF) {
                int kk = idx >> 5, tl = idx & 31;
                const float* xr = &xh[kk * 40 + tl + 1];
                float c = cbs[kk];
                c = fmaf(xr[0], wcs[kk], c);
                c = fmaf(xr[1], wcs[32 + kk], c);
                c = fmaf(xr[2], wcs[64 + kk], c);
                c = fmaf(xr[3], wcs[96 + kk], c);
                convs[kk * 36 + tl] = c;
            }
            __syncthreads();
            #pragma unroll 8
            for (int kk = 0; kk < 32; kk++) {
                float4 a  = *(const float4*)&convs[kk * 36 + ty * 4];
                float4 w0 = *(const float4*)&wls[kk * 128 + tx * 4];
                float4 w1 = *(const float4*)&wls[kk * 128 + 64 + tx * 4];
                float av[4] = {a.x, a.y, a.z, a.w};
                float wv[8] = {w0.x, w0.y, w0.z, w0.w, w1.x, w1.y, w1.z, w1.w};
                #pragma unroll
                for (int i = 0; i < 4; i++)
                    #pragma unroll
                    for (int j = 0; j < 8; j++)
                        acc[i][j] = fmaf(av[i], wv[j], acc[i][j]);
            }
        }
        // epilogue: bias + activation, fp16 store
        const float4 bb0 = *(const float4*)&bp[tx * 4];
        const float4 bb1 = *(const float4*)&bp[64 + tx * 4];
        #pragma unroll
        for (int i = 0; i < 4; i++) {
            size_t row = rowBase + ty * 4 + i;
            store_h4(&projA[row * 128 + tx * 4],
                     softplus_f(acc[i][0] + bb0.x), softplus_f(acc[i][1] + bb0.y),
                     softplus_f(acc[i][2] + bb0.z), softplus_f(acc[i][3] + bb0.w));
            store_h4(&projA[row * 128 + 64 + tx * 4],
                     tanh_f(acc[i][4] + bb1.x), tanh_f(acc[i][5] + bb1.y),
                     tanh_f(acc[i][6] + bb1.z), tanh_f(acc[i][7] + bb1.w));
        }
    } else {
        float acc[4][4];
        #pragma unroll
        for (int i = 0; i < 4; i++)
            #pragma unroll
            for (int j = 0; j < 4; j++) acc[i][j] = 0.0f;

        for (int d0 = 0; d0 < D_; d0 += 32) {
            __syncthreads();
            for (int idx = tid; idx < 288; idx += NTF) {
                int ti = idx >> 3, k4 = idx & 7;
                int t = t0 + ti - 4;
                float4 v = make_float4(0.f, 0.f, 0.f, 0.f);
                if (t >= 0)
                    v = *(const float4*)&x[((size_t)b * L_ + t) * D_ + d0 + k4 * 4];
                xh[(k4 * 4 + 0) * 40 + ti] = v.x;
                xh[(k4 * 4 + 1) * 40 + ti] = v.y;
                xh[(k4 * 4 + 2) * 40 + ti] = v.z;
                xh[(k4 * 4 + 3) * 40 + ti] = v.w;
            }
            // stage Ws chunk [32][64]
            for (int idx = tid; idx < 512; idx += NTF) {
                int kk = idx >> 4, c4 = idx & 15;
                *(float4*)&wls[kk * 64 + c4 * 4] =
                    *(const float4*)&Ws[(size_t)(d0 + kk) * 64 + c4 * 4];
            }
            __syncthreads();
            #pragma unroll 8
            for (int kk = 0; kk < 32; kk++) {
                float4 a  = *(const float4*)&xh[kk * 40 + 4 + ty * 4];
                float4 w0 = *(const float4*)&wls[kk * 64 + tx * 4];
                float av[4] = {a.x, a.y, a.z, a.w};
                float wv[4] = {w0.x, w0.y, w0.z, w0.w};
                #pragma unroll
                for (int i = 0; i < 4; i++)
                    #pragma unroll
                    for (int j = 0; j < 4; j++)
                        acc[i][j] = fmaf(av[i], wv[j], acc[i][j]);
            }
        }
        const float4 bb = *(const float4*)&bs[tx * 4];
        #pragma unroll
        for (int i = 0; i < 4; i++) {
            size_t row = rowBase + ty * 4 + i;
            store_h4(&uA[row * 64 + tx * 4],
                     acc[i][0] + bb.x, acc[i][1] + bb.y,
                     acc[i][2] + bb.z, acc[i][3] + bb.w);
        }
    }
}

// ---------------------------------------------------------------------------
// Kernel 2: combine + transpose. z = dt * Bt * u ; pass Ct through.
// Reads fp16 [B,L,*] natural layout, writes fp16 [B,N,L] transposed.
// ---------------------------------------------------------------------------
__global__ __launch_bounds__(256) void k_combine(
    const __half* __restrict__ projA, const __half* __restrict__ uA,
    const float* __restrict__ dt_log,
    __half* __restrict__ zT, __half* __restrict__ cT)
{
    __shared__ float dts[64];
    __shared__ float zb[64 * 33];
    __shared__ float cb[64 * 33];
    const int tid = threadIdx.x;
    const int t0 = blockIdx.x * 32;
    const int b  = blockIdx.y;
    const size_t base = (size_t)b * L_ + t0;

    if (tid < 64) dts[tid] = softplus_f(dt_log[tid]);
    __syncthreads();

    for (int idx = tid; idx < 2048; idx += 256) {
        int t = idx >> 6, n = idx & 63;
        float Bt = __half2float(projA[(base + t) * 128 + n]);
        float Ct = __half2float(projA[(base + t) * 128 + 64 + n]);
        float uu = __half2float(uA[(base + t) * 64 + n]);
        zb[n * 33 + t] = dts[n] * Bt * uu;
        cb[n * 33 + t] = Ct;
    }
    __syncthreads();

    // write transposed rows: 64 n x 32 tokens, 8 halves (16B) per lane
    {
        int n = tid >> 2, g = tid & 3;
        __half2 hz[4], hc[4];
        #pragma unroll
        for (int k = 0; k < 4; k++) {
            hz[k] = __floats2half2_rn(zb[n * 33 + g * 8 + 2 * k],
                                      zb[n * 33 + g * 8 + 2 * k + 1]);
            hc[k] = __floats2half2_rn(cb[n * 33 + g * 8 + 2 * k],
                                      cb[n * 33 + g * 8 + 2 * k + 1]);
        }
        size_t o = ((size_t)(b * N_ + n)) * L_ + t0 + g * 8;
        *(uint4*)&zT[o] = *(uint4*)hz;
        *(uint4*)&cT[o] = *(uint4*)hc;
    }
}

// ---------------------------------------------------------------------------
// Kernel 3: parallel linear scan (unchanged math, fp16 inputs).
// ---------------------------------------------------------------------------
__global__ __launch_bounds__(64) void k_scan(
    const __half* __restrict__ zT, const __half* __restrict__ cT,
    const float* __restrict__ A_log, const float* __restrict__ dt_log,
    float* __restrict__ yT)
{
    __shared__ float zs[L_];
    __shared__ float cs[L_];
    const int bn = blockIdx.x;
    const int n = bn & (N_ - 1);
    const int lane = threadIdx.x;
    const __half* zp = zT + (size_t)bn * L_;
    const __half* cp = cT + (size_t)bn * L_;

    for (int it = 0; it < 8; it++) {
        int i = lane * 8 + it * 512;
        float4 rz = *(const float4*)(zp + i);
        float4 rc = *(const float4*)(cp + i);
        const __half2* hz = (const __half2*)&rz;
        const __half2* hc = (const __half2*)&rc;
        #pragma unroll
        for (int k = 0; k < 4; k++) {
            float2 fz = __half22float2(hz[k]);
            float2 fc = __half22float2(hc[k]);
            zs[i + 2 * k]     = fz.x;
            zs[i + 2 * k + 1] = fz.y;
            cs[i + 2 * k]     = fc.x;
            cs[i + 2 * k + 1] = fc.y;
        }
    }
    __syncthreads();

    float dtv = softplus_f(dt_log[n]);
    float Av = -softplus_f(A_log[n]);
    float dec = fmaf(dtv, Av, 1.0f);

    float s = 0.0f;
    const int base = lane * 64;
    #pragma unroll
    for (int j = 0; j < 64; j++) s = fmaf(dec, s, zs[base + j]);

    float d2 = dec * dec, d4 = d2 * d2, d8 = d4 * d4;
    float d16 = d8 * d8, d32 = d16 * d16, d64 = d32 * d32;

    float Ag = d64, Bg = s;
    #pragma unroll
    for (int off = 1; off < 64; off <<= 1) {
        float Ap = __shfl_up(Ag, off);
        float Bp = __shfl_up(Bg, off);
        if (lane >= off) { Bg = fmaf(Ag, Bp, Bg); Ag *= Ap; }
    }
    float carry = __shfl_up(Bg, 1);
    if (lane == 0) carry = 0.0f;

    float st = carry;
    #pragma unroll
    for (int j = 0; j < 64; j++) {
        st = fmaf(dec, st, zs[base + j]);
        zs[base + j] = cs[base + j] * st;
    }
    __syncthreads();
    float* yp = yT + (size_t)bn * L_;
    for (int i = lane * 4; i < L_; i += 64 * 4)
        *(float4*)&yp[i] = *(const float4*)&zs[i];
}

// ---------------------------------------------------------------------------
// Kernel 4: out = y @ Wo + bo. 64 tokens x 128 dims, K = 64.
// Conflict-free weight reads: col groups of 4 at +0 and +64.
// ---------------------------------------------------------------------------
__global__ __launch_bounds__(256) void k_out(
    const float* __restrict__ yT, const float* __restrict__ Wo,
    const float* __restrict__ bo, float* __restrict__ out)
{
    __shared__ float ysv[N_ * 68];
    __shared__ float wos[N_ * 128];
    const int tid = threadIdx.x;
    const int tx = tid & 15;
    const int ty = tid >> 4;
    const int d0 = blockIdx.x * 128;
    const int l0 = blockIdx.y * 64;
    const int b  = blockIdx.z;

    for (int idx = tid; idx < N_ * 64; idx += 256) {
        int nn = idx >> 6, li = idx & 63;
        ysv[nn * 68 + li] = yT[((size_t)(b * N_ + nn)) * L_ + l0 + li];
    }
    for (int idx = tid; idx < N_ * 128; idx += 256) {
        int nn = idx >> 7, dd = idx & 127;
        wos[idx] = Wo[nn * D_ + d0 + dd];
    }
    __syncthreads();

    float acc[4][8];
    #pragma unroll
    for (int i = 0; i < 4; i++)
        #pragma unroll
        for (int j = 0; j < 8; j++) acc[i][j] = 0.0f;

    #pragma unroll 8
    for (int nn = 0; nn < N_; nn++) {
        float4 a  = *(const float4*)&ysv[nn * 68 + ty * 4];
        float4 w0 = *(const float4*)&wos[nn * 128 + tx * 4];
        float4 w1 = *(const float4*)&wos[nn * 128 + 64 + tx * 4];
        float av[4] = {a.x, a.y, a.z, a.w};
        float wv[8] = {w0.x, w0.y, w0.z, w0.w, w1.x, w1.y, w1.z, w1.w};
        #pragma unroll
        for (int i = 0; i < 4; i++)
            #pragma unroll
            for (int j = 0; j < 8; j++)
                acc[i][j] = fmaf(av[i], wv[j], acc[i][j]);
    }

    const float4 b0 = *(const float4*)&bo[d0 + tx * 4];
    const float4 b1 = *(const float4*)&bo[d0 + 64 + tx * 4];
    #pragma unroll
    for (int i = 0; i < 4; i++) {
        size_t o = ((size_t)b * L_ + l0 + ty * 4 + i) * D_ + d0;
        float4 o0 = {acc[i][0] + b0.x, acc[i][1] + b0.y,
                     acc[i][2] + b0.z, acc[i][3] + b0.w};
        float4 o1 = {acc[i][4] + b1.x, acc[i][5] + b1.y,
                     acc[i][6] + b1.z, acc[i][7] + b1.w};
        *(float4*)(out + o + tx * 4) = o0;
        *(float4*)(out + o + 64 + tx * 4) = o1;
    }
}

// ---------------------------------------------------------------------------
extern "C" void kernel_launch(void* const* d_in, const int* in_sizes, int n_in,
                              void* d_out, int out_size, void* d_ws, size_t ws_size,
                              hipStream_t stream) {
    const float* x      = (const float*)d_in[0];
    const float* conv_w = (const float*)d_in[1];
    const float* conv_b = (const float*)d_in[2];
    const float* Wp     = (const float*)d_in[3];
    const float* bp     = (const float*)d_in[4];
    const float* Ws     = (const float*)d_in[5];
    const float* bs     = (const float*)d_in[6];
    const float* A_log  = (const float*)d_in[7];
    const float* dt_log = (const float*)d_in[8];
    const float* Wo     = (const float*)d_in[9];
    const float* bo     = (const float*)d_in[10];
    float* out = (float*)d_out;

    char* w = (char*)d_ws;
    __half* projA = (__half*)w;                      // 4 MB  [B,L,128]
    __half* uA    = (__half*)(w + 4194304);          // 2 MB  [B,L,64]
    __half* zT    = (__half*)(w + 6291456);          // 2 MB  [B,N,L]
    __half* cT    = (__half*)(w + 8388608);          // 2 MB  [B,N,L]
    float*  yT    = (float*)w;                       // 4 MB, aliases projA (dead by then)

    k_frontend<<<dim3(512, 2), dim3(NTF), 0, stream>>>(
        x, conv_w, conv_b, Wp, bp, Ws, bs, projA, uA);
    k_combine<<<dim3(L_ / 32, B_), dim3(256), 0, stream>>>(
        projA, uA, dt_log, zT, cT);
    k_scan<<<dim3(B_ * N_), dim3(64), 0, stream>>>(zT, cT, A_log, dt_log, yT);
    k_out<<<dim3(D_ / 128, L_ / 64, B_), dim3(256), 0, stream>>>(yT, Wo, bo, out);
}

// Round 3
// 252.079 us; speedup vs baseline: 2.1769x; 1.6029x over previous
//
#include <hip/hip_runtime.h>

#define B_ 4
#define L_ 4096
#define D_ 1024
#define N_ 64

typedef _Float16 f16;
typedef __attribute__((ext_vector_type(8))) _Float16 half8;
typedef __attribute__((ext_vector_type(4))) float f32x4;

__device__ __forceinline__ float softplus_f(float x) {
    return fmaxf(x, 0.0f) + log1pf(__expf(-fabsf(x)));
}

__device__ __forceinline__ float tanh_f(float x) {
    float xc = fminf(fmaxf(x, -15.0f), 15.0f);
    float e = __expf(2.0f * xc);
    return (e - 1.0f) / (e + 1.0f);
}

// ---------------------------------------------------------------------------
// Prep: transpose weights to fp16, k-contiguous rows.
// WT [192][1024]: rows 0-127 = Wp columns, rows 128-191 = Ws columns.
// WoT [1024][64]: WoT[d][n] = Wo[n][d].
// ---------------------------------------------------------------------------
__global__ __launch_bounds__(256) void k_prepw(
    const float* __restrict__ Wp, const float* __restrict__ Ws,
    const float* __restrict__ Wo, f16* __restrict__ WT, f16* __restrict__ WoT)
{
    int gid = blockIdx.x * 256 + threadIdx.x;
    if (gid < 24576) {                       // WT: 192 rows x 128 k-groups
        int r = gid >> 7, kg = gid & 127;
        const float* src; int ncol, c;
        if (r < 128) { src = Wp; ncol = 128; c = r; }
        else         { src = Ws; ncol = 64;  c = r - 128; }
        f16 h[8];
        #pragma unroll
        for (int j = 0; j < 8; j++)
            h[j] = (f16)src[(size_t)(kg * 8 + j) * ncol + c];
        *(uint4*)&WT[(size_t)r * 1024 + kg * 8] = *(uint4*)h;
    } else if (gid < 24576 + 8192) {         // WoT: 1024 d x 8 n-groups
        int g2 = gid - 24576;
        int d = g2 >> 3, ng = g2 & 7;
        f16 h[8];
        #pragma unroll
        for (int j = 0; j < 8; j++)
            h[j] = (f16)Wo[(size_t)(ng * 8 + j) * D_ + d];
        *(uint4*)&WoT[(size_t)d * 64 + ng * 8] = *(uint4*)h;
    }
}

// ---------------------------------------------------------------------------
// GEMM1 (MFMA fp16, no LDS): one wave per 32-token x 64-col tile.
// grid (512 token-tiles, 3): y=0 -> Bt=softplus(conv@Wp[:,0:64]+bp[0:64])
//                            y=1 -> Ct=tanh   (conv@Wp[:,64:128]+bp[64:128])
//                            y=2 -> u = x@Ws+bs
// D[m=col][n=token]; A-frag = WT rows (k-contig), B-frag built from x
// (conv applied on the fly for y<2). All frags loaded straight from global.
// ---------------------------------------------------------------------------
__global__ __launch_bounds__(64) void k_gemm1(
    const float* __restrict__ x, const float* __restrict__ conv_w,
    const float* __restrict__ conv_b, const f16* __restrict__ WT,
    const float* __restrict__ bp, const float* __restrict__ bs,
    f16* __restrict__ BtH, f16* __restrict__ CtH, f16* __restrict__ uH)
{
    const int lane = threadIdx.x;
    const int r = lane & 15, q = lane >> 4;
    const int g = blockIdx.y;
    const int t0 = blockIdx.x * 32;
    const int cbase = g * 64;

    f32x4 acc[4][2] = {};

    for (int k0 = 0; k0 < D_; k0 += 32) {
        const int kk = k0 + q * 8;
        half8 a[4];
        #pragma unroll
        for (int mt = 0; mt < 4; mt++)
            a[mt] = *(const half8*)&WT[(size_t)(cbase + mt * 16 + r) * 1024 + kk];

        half8 b[2];
        if (g == 2) {
            #pragma unroll
            for (int nt = 0; nt < 2; nt++) {
                const int t = t0 + nt * 16 + r;
                const float* xp = &x[(size_t)t * D_ + kk];
                float4 v0 = *(const float4*)xp;
                float4 v1 = *(const float4*)(xp + 4);
                half8 h;
                h[0] = (f16)v0.x; h[1] = (f16)v0.y; h[2] = (f16)v0.z; h[3] = (f16)v0.w;
                h[4] = (f16)v1.x; h[5] = (f16)v1.y; h[6] = (f16)v1.z; h[7] = (f16)v1.w;
                b[nt] = h;
            }
        } else {
            // conv weights for lag j: conv[t] = cb + sum_j w[3-j]*x[t-j]
            float cw[4][8];
            #pragma unroll
            for (int j = 0; j < 4; j++) {
                float4 w0 = *(const float4*)&conv_w[(3 - j) * D_ + kk];
                float4 w1 = *(const float4*)&conv_w[(3 - j) * D_ + kk + 4];
                cw[j][0] = w0.x; cw[j][1] = w0.y; cw[j][2] = w0.z; cw[j][3] = w0.w;
                cw[j][4] = w1.x; cw[j][5] = w1.y; cw[j][6] = w1.z; cw[j][7] = w1.w;
            }
            float4 cb0 = *(const float4*)&conv_b[kk];
            float4 cb1 = *(const float4*)&conv_b[kk + 4];
            #pragma unroll
            for (int nt = 0; nt < 2; nt++) {
                const int t = t0 + nt * 16 + r;
                const int l = t & (L_ - 1);
                float s[8] = {cb0.x, cb0.y, cb0.z, cb0.w, cb1.x, cb1.y, cb1.z, cb1.w};
                #pragma unroll
                for (int j = 0; j < 4; j++) {
                    if (l >= j) {
                        const float* xp = &x[(size_t)(t - j) * D_ + kk];
                        float4 v0 = *(const float4*)xp;
                        float4 v1 = *(const float4*)(xp + 4);
                        s[0] = fmaf(v0.x, cw[j][0], s[0]);
                        s[1] = fmaf(v0.y, cw[j][1], s[1]);
                        s[2] = fmaf(v0.z, cw[j][2], s[2]);
                        s[3] = fmaf(v0.w, cw[j][3], s[3]);
                        s[4] = fmaf(v1.x, cw[j][4], s[4]);
                        s[5] = fmaf(v1.y, cw[j][5], s[5]);
                        s[6] = fmaf(v1.z, cw[j][6], s[6]);
                        s[7] = fmaf(v1.w, cw[j][7], s[7]);
                    }
                }
                half8 h;
                #pragma unroll
                for (int u = 0; u < 8; u++) h[u] = (f16)s[u];
                b[nt] = h;
            }
        }
        #pragma unroll
        for (int mt = 0; mt < 4; mt++)
            #pragma unroll
            for (int nt = 0; nt < 2; nt++)
                acc[mt][nt] = __builtin_amdgcn_mfma_f32_16x16x32_f16(
                    a[mt], b[nt], acc[mt][nt], 0, 0, 0);
    }

    // epilogue: bias + activation + fp16 store (token-major [t][64])
    f16* outp = (g == 0) ? BtH : (g == 1 ? CtH : uH);
    const float* bias = (g == 2) ? bs : bp;
    const int bofs = (g == 1) ? 64 : 0;
    #pragma unroll
    for (int mt = 0; mt < 4; mt++) {
        const int mbase = mt * 16 + q * 4;
        const float4 bb = *(const float4*)&bias[bofs + mbase];
        #pragma unroll
        for (int nt = 0; nt < 2; nt++) {
            const int t = t0 + nt * 16 + r;
            float v[4] = {acc[mt][nt][0] + bb.x, acc[mt][nt][1] + bb.y,
                          acc[mt][nt][2] + bb.z, acc[mt][nt][3] + bb.w};
            if (g == 0) {
                #pragma unroll
                for (int i = 0; i < 4; i++) v[i] = softplus_f(v[i]);
            } else if (g == 1) {
                #pragma unroll
                for (int i = 0; i < 4; i++) v[i] = tanh_f(v[i]);
            }
            f16 h[4] = {(f16)v[0], (f16)v[1], (f16)v[2], (f16)v[3]};
            *(uint2*)&outp[(size_t)t * 64 + mbase] = *(uint2*)h;
        }
    }
}

// ---------------------------------------------------------------------------
// Combine: z = dt[n]*Bt*u, pass Ct; transpose token-major -> n-major fp16.
// ---------------------------------------------------------------------------
__global__ __launch_bounds__(256) void k_combine(
    const f16* __restrict__ BtH, const f16* __restrict__ CtH,
    const f16* __restrict__ uH, const float* __restrict__ dt_log,
    f16* __restrict__ zT, f16* __restrict__ cT)
{
    __shared__ float dts[64];
    __shared__ float zb[64 * 33];
    __shared__ float cb[64 * 33];
    const int tid = threadIdx.x;
    const int t0 = blockIdx.x * 32;
    const int b  = blockIdx.y;
    const size_t base = (size_t)b * L_ + t0;

    if (tid < 64) dts[tid] = softplus_f(dt_log[tid]);
    __syncthreads();

    {
        int t = tid >> 3, ng = tid & 7;
        uint4 ub = *(const uint4*)&BtH[(base + t) * 64 + ng * 8];
        uint4 uu = *(const uint4*)&uH[(base + t) * 64 + ng * 8];
        uint4 uc = *(const uint4*)&CtH[(base + t) * 64 + ng * 8];
        const f16* hb = (const f16*)&ub;
        const f16* hu = (const f16*)&uu;
        const f16* hc = (const f16*)&uc;
        #pragma unroll
        for (int j = 0; j < 8; j++) {
            int n = ng * 8 + j;
            zb[n * 33 + t] = dts[n] * (float)hb[j] * (float)hu[j];
            cb[n * 33 + t] = (float)hc[j];
        }
    }
    __syncthreads();
    {
        int n = tid >> 2, g4 = tid & 3;
        f16 hz[8], hc[8];
        #pragma unroll
        for (int k = 0; k < 8; k++) {
            hz[k] = (f16)zb[n * 33 + g4 * 8 + k];
            hc[k] = (f16)cb[n * 33 + g4 * 8 + k];
        }
        size_t o = ((size_t)(b * N_ + n)) * L_ + t0 + g4 * 8;
        *(uint4*)&zT[o] = *(uint4*)hz;
        *(uint4*)&cT[o] = *(uint4*)hc;
    }
}

// ---------------------------------------------------------------------------
// Scan: one wave per (b,n) chain; exact affine chunk-stitched scan.
// Writes yH fp16 n-major.
// ---------------------------------------------------------------------------
__global__ __launch_bounds__(64) void k_scan(
    const f16* __restrict__ zT, const f16* __restrict__ cT,
    const float* __restrict__ A_log, const float* __restrict__ dt_log,
    f16* __restrict__ yH)
{
    __shared__ float zs[L_];
    __shared__ float cs[L_];
    const int bn = blockIdx.x;
    const int n = bn & (N_ - 1);
    const int lane = threadIdx.x;
    const f16* zp = zT + (size_t)bn * L_;
    const f16* cp = cT + (size_t)bn * L_;

    for (int it = 0; it < 8; it++) {
        int i = lane * 8 + it * 512;
        uint4 rz = *(const uint4*)(zp + i);
        uint4 rc = *(const uint4*)(cp + i);
        const f16* hz = (const f16*)&rz;
        const f16* hc = (const f16*)&rc;
        #pragma unroll
        for (int k = 0; k < 8; k++) {
            zs[i + k] = (float)hz[k];
            cs[i + k] = (float)hc[k];
        }
    }
    __syncthreads();

    float dtv = softplus_f(dt_log[n]);
    float Av = -softplus_f(A_log[n]);
    float dec = fmaf(dtv, Av, 1.0f);

    float s = 0.0f;
    const int base = lane * 64;
    #pragma unroll
    for (int j = 0; j < 64; j++) s = fmaf(dec, s, zs[base + j]);

    float d2 = dec * dec, d4 = d2 * d2, d8 = d4 * d4;
    float d16 = d8 * d8, d32 = d16 * d16, d64 = d32 * d32;

    float Ag = d64, Bg = s;
    #pragma unroll
    for (int off = 1; off < 64; off <<= 1) {
        float Ap = __shfl_up(Ag, off);
        float Bp = __shfl_up(Bg, off);
        if (lane >= off) { Bg = fmaf(Ag, Bp, Bg); Ag *= Ap; }
    }
    float carry = __shfl_up(Bg, 1);
    if (lane == 0) carry = 0.0f;

    float st = carry;
    #pragma unroll
    for (int j = 0; j < 64; j++) {
        st = fmaf(dec, st, zs[base + j]);
        zs[base + j] = cs[base + j] * st;
    }
    __syncthreads();
    f16* yp = yH + (size_t)bn * L_;
    for (int i = lane * 8; i < L_; i += 512) {
        f16 h[8];
        #pragma unroll
        for (int k = 0; k < 8; k++) h[k] = (f16)zs[i + k];
        *(uint4*)&yp[i] = *(uint4*)h;
    }
}

// ---------------------------------------------------------------------------
// Out GEMM (MFMA fp16): out[t][d] = y[t][:] @ Wo[:,d] + bo. K = 64.
// Block: 4 waves, 64 tokens x 128 d (wave = 64 tok x 32 d).
// A-frag from LDS ys[t][n] (transposed from yH n-major, conflict-free),
// B-frag direct from WoT[d][n]. D[m=tok][n=d] -> coalesced f32 stores.
// ---------------------------------------------------------------------------
__global__ __launch_bounds__(256) void k_out(
    const f16* __restrict__ yH, const f16* __restrict__ WoT,
    const float* __restrict__ bo, float* __restrict__ out)
{
    __shared__ f16 ys[64 * 72];
    const int tid = threadIdx.x;
    const int w = tid >> 6, lane = tid & 63;
    const int r = lane & 15, q = lane >> 4;
    const int T0 = blockIdx.x * 64;
    const int b = T0 >> 12, l0 = T0 & (L_ - 1);
    const int d0 = blockIdx.y * 128 + w * 32;

    // stage transposed y tile: thread -> (n = tid&63, tg = tid>>6 + 4c)
    #pragma unroll
    for (int c = 0; c < 2; c++) {
        int n = tid & 63, tg = (tid >> 6) + c * 4;
        uint4 v = *(const uint4*)&yH[((size_t)(b * N_ + n)) * L_ + l0 + tg * 8];
        const f16* h = (const f16*)&v;
        #pragma unroll
        for (int j = 0; j < 8; j++) ys[(tg * 8 + j) * 72 + n] = h[j];
    }
    __syncthreads();

    f32x4 acc[4][2] = {};
    #pragma unroll
    for (int ks = 0; ks < 2; ks++) {
        const int k = ks * 32 + q * 8;
        half8 bfr[2];
        #pragma unroll
        for (int nt = 0; nt < 2; nt++)
            bfr[nt] = *(const half8*)&WoT[(size_t)(d0 + nt * 16 + r) * 64 + k];
        #pragma unroll
        for (int mt = 0; mt < 4; mt++) {
            half8 afr = *(const half8*)&ys[(mt * 16 + r) * 72 + k];
            #pragma unroll
            for (int nt = 0; nt < 2; nt++)
                acc[mt][nt] = __builtin_amdgcn_mfma_f32_16x16x32_f16(
                    afr, bfr[nt], acc[mt][nt], 0, 0, 0);
        }
    }

    #pragma unroll
    for (int nt = 0; nt < 2; nt++) {
        const int d = d0 + nt * 16 + r;
        const float bv = bo[d];
        #pragma unroll
        for (int mt = 0; mt < 4; mt++) {
            #pragma unroll
            for (int ri = 0; ri < 4; ri++) {
                const int t = T0 + mt * 16 + q * 4 + ri;
                out[(size_t)t * D_ + d] = acc[mt][nt][ri] + bv;
            }
        }
    }
}

// ---------------------------------------------------------------------------
extern "C" void kernel_launch(void* const* d_in, const int* in_sizes, int n_in,
                              void* d_out, int out_size, void* d_ws, size_t ws_size,
                              hipStream_t stream) {
    const float* x      = (const float*)d_in[0];
    const float* conv_w = (const float*)d_in[1];
    const float* conv_b = (const float*)d_in[2];
    const float* Wp     = (const float*)d_in[3];
    const float* bp     = (const float*)d_in[4];
    const float* Ws     = (const float*)d_in[5];
    const float* bs     = (const float*)d_in[6];
    const float* A_log  = (const float*)d_in[7];
    const float* dt_log = (const float*)d_in[8];
    const float* Wo     = (const float*)d_in[9];
    const float* bo     = (const float*)d_in[10];
    float* out = (float*)d_out;

    char* w = (char*)d_ws;
    f16* WT  = (f16*)w;                       // 384 KB [192][1024]
    f16* WoT = (f16*)(w + 393216);            // 128 KB [1024][64]
    f16* BtH = (f16*)(w + 524288);            // 2 MB [B,L,64]
    f16* CtH = (f16*)(w + 2621440);           // 2 MB
    f16* uH  = (f16*)(w + 4718592);           // 2 MB
    f16* zT  = (f16*)(w + 6815744);           // 2 MB [B,N,L]
    f16* cT  = (f16*)(w + 8912896);           // 2 MB
    f16* yH  = BtH;                           // alias: BtH dead after combine

    k_prepw<<<dim3(128), dim3(256), 0, stream>>>(Wp, Ws, Wo, WT, WoT);
    k_gemm1<<<dim3(512, 3), dim3(64), 0, stream>>>(
        x, conv_w, conv_b, WT, bp, bs, BtH, CtH, uH);
    k_combine<<<dim3(L_ / 32, B_), dim3(256), 0, stream>>>(
        BtH, CtH, uH, dt_log, zT, cT);
    k_scan<<<dim3(B_ * N_), dim3(64), 0, stream>>>(zT, cT, A_log, dt_log, yH);
    k_out<<<dim3(B_ * L_ / 64, D_ / 128), dim3(256), 0, stream>>>(yH, WoT, bo, out);
}

// Round 4
// 201.161 us; speedup vs baseline: 2.7280x; 1.2531x over previous
//
#include <hip/hip_runtime.h>

#define B_ 4
#define L_ 4096
#define D_ 1024
#define N_ 64

typedef _Float16 f16;
typedef __attribute__((ext_vector_type(8))) _Float16 half8;
typedef __attribute__((ext_vector_type(4))) float f32x4;

__device__ __forceinline__ float softplus_f(float x) {
    return fmaxf(x, 0.0f) + log1pf(__expf(-fabsf(x)));
}

__device__ __forceinline__ float tanh_f(float x) {
    float xc = fminf(fmaxf(x, -15.0f), 15.0f);
    float e = __expf(2.0f * xc);
    return (e - 1.0f) / (e + 1.0f);
}

// ---------------------------------------------------------------------------
// Prep: WT [192][1024] fp16 (rows 0-127 = Wp cols, 128-191 = Ws cols);
// WoT [1024][64] fp16 (WoT[d][n] = Wo[n][d]).
// ---------------------------------------------------------------------------
__global__ __launch_bounds__(256) void k_prepw(
    const float* __restrict__ Wp, const float* __restrict__ Ws,
    const float* __restrict__ Wo, f16* __restrict__ WT, f16* __restrict__ WoT)
{
    int gid = blockIdx.x * 256 + threadIdx.x;
    if (gid < 24576) {
        int r = gid >> 7, kg = gid & 127;
        const float* src; int ncol, c;
        if (r < 128) { src = Wp; ncol = 128; c = r; }
        else         { src = Ws; ncol = 64;  c = r - 128; }
        f16 h[8];
        #pragma unroll
        for (int j = 0; j < 8; j++)
            h[j] = (f16)src[(size_t)(kg * 8 + j) * ncol + c];
        *(uint4*)&WT[(size_t)r * 1024 + kg * 8] = *(uint4*)h;
    } else {
        int g2 = gid - 24576;                 // < 8192
        int d = g2 >> 3, ng = g2 & 7;
        f16 h[8];
        #pragma unroll
        for (int j = 0; j < 8; j++)
            h[j] = (f16)Wo[(size_t)(ng * 8 + j) * D_ + d];
        *(uint4*)&WoT[(size_t)d * 64 + ng * 8] = *(uint4*)h;
    }
}

// ---------------------------------------------------------------------------
// Fused frontend: per block (256 thr / 4 waves) = 32 tokens x 192 cols.
// cols 0-63: Bt = softplus(conv@Wp+bp), 64-127: Ct = tanh(conv@Wp+bp),
// 128-191: u = x@Ws+bs.  Wave w owns cols w*48..w*48+47 (3 m-frags) x
// 32 tokens (2 n-frags).  x chunk (36 rows x 64 dims) staged in LDS fp16
// with register prefetch; conv b-frags built in-reg (4 shifted LDS rows).
// Epilogue fuses combine: z = dt*Bt*u, writes zT/cT n-major fp16.
// ---------------------------------------------------------------------------
__global__ __launch_bounds__(256) void k_frontend(
    const float* __restrict__ x, const float* __restrict__ conv_w,
    const float* __restrict__ conv_b, const f16* __restrict__ WT,
    const float* __restrict__ bp, const float* __restrict__ bs,
    const float* __restrict__ dt_log,
    f16* __restrict__ zT, f16* __restrict__ cT)
{
    __shared__ __align__(16) f16 xh[36 * 72];   // rows t0-4..t0+31, stride 72
    __shared__ float sE[3 * 32 * 68];           // Bt/Ct/u [t][cl], stride 68

    const int tid = threadIdx.x;
    const int w = tid >> 6, lane = tid & 63;
    const int r = lane & 15, q = lane >> 4;
    const int T0 = blockIdx.x * 32;
    const int bb = T0 >> 12;
    const int l0 = T0 & (L_ - 1);
    const int cw0 = w * 48;

    f32x4 acc[3][2] = {};
    float4 rA[3];

    // --- staging helpers (36 rows x 16 float4) ---
    #define LDX(c0)                                                          \
        {                                                                    \
            _Pragma("unroll")                                                \
            for (int s = 0; s < 3; s++) {                                    \
                int idx = tid + 256 * s;                                     \
                float4 v = make_float4(0.f, 0.f, 0.f, 0.f);                  \
                if (idx < 576) {                                             \
                    int row = idx >> 4, g = idx & 15;                        \
                    int l = l0 + row - 4;                                    \
                    if (l >= 0)                                              \
                        v = *(const float4*)&x[((size_t)(bb * L_ + l)) * D_  \
                                               + (c0) + g * 4];              \
                }                                                            \
                rA[s] = v;                                                   \
            }                                                                \
        }

    LDX(0);
    for (int c = 0; c < 16; c++) {
        __syncthreads();
        #pragma unroll
        for (int s = 0; s < 3; s++) {
            int idx = tid + 256 * s;
            if (idx < 576) {
                int row = idx >> 4, g = idx & 15;
                f16 h[4] = {(f16)rA[s].x, (f16)rA[s].y, (f16)rA[s].z, (f16)rA[s].w};
                *(uint2*)&xh[row * 72 + g * 4] = *(uint2*)h;
            }
        }
        __syncthreads();
        if (c < 15) LDX((c + 1) * 64);

        const int k0 = c * 64;
        #pragma unroll
        for (int ks = 0; ks < 2; ks++) {
            const int kk = k0 + ks * 32 + q * 8;   // global k
            const int kl = ks * 32 + q * 8;        // k within chunk

            half8 af[3];
            #pragma unroll
            for (int mf = 0; mf < 3; mf++)
                af[mf] = *(const half8*)&WT[(size_t)(cw0 + mf * 16 + r) * 1024 + kk];

            float cw3[8], cw2[8], cw1[8], cw0v[8], cbv[8];
            if (w < 3) {
                float4 a0 = *(const float4*)&conv_w[3 * D_ + kk];
                float4 a1 = *(const float4*)&conv_w[3 * D_ + kk + 4];
                float4 b0 = *(const float4*)&conv_w[2 * D_ + kk];
                float4 b1 = *(const float4*)&conv_w[2 * D_ + kk + 4];
                float4 c0v = *(const float4*)&conv_w[1 * D_ + kk];
                float4 c1v = *(const float4*)&conv_w[1 * D_ + kk + 4];
                float4 d0v = *(const float4*)&conv_w[0 * D_ + kk];
                float4 d1v = *(const float4*)&conv_w[0 * D_ + kk + 4];
                float4 e0 = *(const float4*)&conv_b[kk];
                float4 e1 = *(const float4*)&conv_b[kk + 4];
                cw3[0]=a0.x;cw3[1]=a0.y;cw3[2]=a0.z;cw3[3]=a0.w;cw3[4]=a1.x;cw3[5]=a1.y;cw3[6]=a1.z;cw3[7]=a1.w;
                cw2[0]=b0.x;cw2[1]=b0.y;cw2[2]=b0.z;cw2[3]=b0.w;cw2[4]=b1.x;cw2[5]=b1.y;cw2[6]=b1.z;cw2[7]=b1.w;
                cw1[0]=c0v.x;cw1[1]=c0v.y;cw1[2]=c0v.z;cw1[3]=c0v.w;cw1[4]=c1v.x;cw1[5]=c1v.y;cw1[6]=c1v.z;cw1[7]=c1v.w;
                cw0v[0]=d0v.x;cw0v[1]=d0v.y;cw0v[2]=d0v.z;cw0v[3]=d0v.w;cw0v[4]=d1v.x;cw0v[5]=d1v.y;cw0v[6]=d1v.z;cw0v[7]=d1v.w;
                cbv[0]=e0.x;cbv[1]=e0.y;cbv[2]=e0.z;cbv[3]=e0.w;cbv[4]=e1.x;cbv[5]=e1.y;cbv[6]=e1.z;cbv[7]=e1.w;
            }

            half8 braw[2], bcnv[2];
            #pragma unroll
            for (int nf = 0; nf < 2; nf++) {
                const int rb = nf * 16 + r + 4;
                half8 h0 = *(const half8*)&xh[rb * 72 + kl];
                braw[nf] = h0;
                if (w < 3) {
                    half8 h1 = *(const half8*)&xh[(rb - 1) * 72 + kl];
                    half8 h2 = *(const half8*)&xh[(rb - 2) * 72 + kl];
                    half8 h3 = *(const half8*)&xh[(rb - 3) * 72 + kl];
                    half8 hc;
                    #pragma unroll
                    for (int u = 0; u < 8; u++) {
                        float s0 = cbv[u];
                        s0 = fmaf(cw3[u], (float)h0[u], s0);
                        s0 = fmaf(cw2[u], (float)h1[u], s0);
                        s0 = fmaf(cw1[u], (float)h2[u], s0);
                        s0 = fmaf(cw0v[u], (float)h3[u], s0);
                        hc[u] = (f16)s0;
                    }
                    bcnv[nf] = hc;
                }
            }

            #pragma unroll
            for (int mf = 0; mf < 3; mf++) {
                const bool useConv = (cw0 + mf * 16) < 128;
                #pragma unroll
                for (int nf = 0; nf < 2; nf++)
                    acc[mf][nf] = __builtin_amdgcn_mfma_f32_16x16x32_f16(
                        af[mf], useConv ? bcnv[nf] : braw[nf], acc[mf][nf], 0, 0, 0);
            }
        }
    }

    // --- epilogue: bias + activation -> sE ---
    float* sB = sE;
    float* sC = sE + 32 * 68;
    float* sU = sE + 2 * 32 * 68;
    __syncthreads();
    #pragma unroll
    for (int mf = 0; mf < 3; mf++) {
        const int cb4 = cw0 + mf * 16 + q * 4;
        const int seg = cb4 >> 6;          // 0=Bt 1=Ct 2=u (frag-uniform)
        const int cl = cb4 & 63;
        const float4 bb4 = (seg == 2) ? *(const float4*)&bs[cl]
                                      : *(const float4*)&bp[cb4];
        float* dst = (seg == 0) ? sB : (seg == 1 ? sC : sU);
        #pragma unroll
        for (int nf = 0; nf < 2; nf++) {
            const int t = nf * 16 + r;
            float v0 = acc[mf][nf][0] + bb4.x;
            float v1 = acc[mf][nf][1] + bb4.y;
            float v2 = acc[mf][nf][2] + bb4.z;
            float v3 = acc[mf][nf][3] + bb4.w;
            if (seg == 0) {
                v0 = softplus_f(v0); v1 = softplus_f(v1);
                v2 = softplus_f(v2); v3 = softplus_f(v3);
            } else if (seg == 1) {
                v0 = tanh_f(v0); v1 = tanh_f(v1);
                v2 = tanh_f(v2); v3 = tanh_f(v3);
            }
            float4 vv = {v0, v1, v2, v3};
            *(float4*)&dst[t * 68 + cl] = vv;
        }
    }
    __syncthreads();

    // --- fused combine: z = dt[n]*Bt*u, store zT/cT n-major ---
    {
        const int n = tid >> 2, tg = tid & 3;
        const float dtv = softplus_f(dt_log[n]);
        f16 hz[8], hc[8];
        #pragma unroll
        for (int j = 0; j < 8; j++) {
            const int t = tg * 8 + j;
            hz[j] = (f16)(dtv * sB[t * 68 + n] * sU[t * 68 + n]);
            hc[j] = (f16)sC[t * 68 + n];
        }
        size_t o = ((size_t)(bb * N_ + n)) * L_ + l0 + tg * 8;
        *(uint4*)&zT[o] = *(uint4*)hz;
        *(uint4*)&cT[o] = *(uint4*)hc;
    }
    #undef LDX
}

// ---------------------------------------------------------------------------
// Scan: one wave per (b,n) chain; exact affine chunk-stitched scan.
// ---------------------------------------------------------------------------
__global__ __launch_bounds__(64) void k_scan(
    const f16* __restrict__ zT, const f16* __restrict__ cT,
    const float* __restrict__ A_log, const float* __restrict__ dt_log,
    f16* __restrict__ yH)
{
    __shared__ float zs[L_];
    __shared__ float cs[L_];
    const int bn = blockIdx.x;
    const int n = bn & (N_ - 1);
    const int lane = threadIdx.x;
    const f16* zp = zT + (size_t)bn * L_;
    const f16* cp = cT + (size_t)bn * L_;

    for (int it = 0; it < 8; it++) {
        int i = lane * 8 + it * 512;
        uint4 rz = *(const uint4*)(zp + i);
        uint4 rc = *(const uint4*)(cp + i);
        const f16* hz = (const f16*)&rz;
        const f16* hc = (const f16*)&rc;
        #pragma unroll
        for (int k = 0; k < 8; k++) {
            zs[i + k] = (float)hz[k];
            cs[i + k] = (float)hc[k];
        }
    }
    __syncthreads();

    float dtv = softplus_f(dt_log[n]);
    float Av = -softplus_f(A_log[n]);
    float dec = fmaf(dtv, Av, 1.0f);

    float s = 0.0f;
    const int base = lane * 64;
    #pragma unroll
    for (int j = 0; j < 64; j++) s = fmaf(dec, s, zs[base + j]);

    float d2 = dec * dec, d4 = d2 * d2, d8 = d4 * d4;
    float d16 = d8 * d8, d32 = d16 * d16, d64 = d32 * d32;

    float Ag = d64, Bg = s;
    #pragma unroll
    for (int off = 1; off < 64; off <<= 1) {
        float Ap = __shfl_up(Ag, off);
        float Bp = __shfl_up(Bg, off);
        if (lane >= off) { Bg = fmaf(Ag, Bp, Bg); Ag *= Ap; }
    }
    float carry = __shfl_up(Bg, 1);
    if (lane == 0) carry = 0.0f;

    float st = carry;
    #pragma unroll
    for (int j = 0; j < 64; j++) {
        st = fmaf(dec, st, zs[base + j]);
        zs[base + j] = cs[base + j] * st;
    }
    __syncthreads();
    f16* yp = yH + (size_t)bn * L_;
    for (int i = lane * 8; i < L_; i += 512) {
        f16 h[8];
        #pragma unroll
        for (int k = 0; k < 8; k++) h[k] = (f16)zs[i + k];
        *(uint4*)&yp[i] = *(uint4*)h;
    }
}

// ---------------------------------------------------------------------------
// Out GEMM: out[t][d] = y[t][:] @ Wo[:,d] + bo.  A = WoT (m=d), B = y (n=tok)
// -> D rows are d -> float4 coalesced stores.  Block 256 thr: 64 tok x 128 d,
// wave = 32 d x 64 tok.  Grid (256, 8) = 2048 blocks = 8/CU.
// ---------------------------------------------------------------------------
__global__ __launch_bounds__(256) void k_out(
    const f16* __restrict__ yH, const f16* __restrict__ WoT,
    const float* __restrict__ bo, float* __restrict__ out)
{
    __shared__ __align__(16) f16 ys[64 * 72];
    const int tid = threadIdx.x;
    const int w = tid >> 6, lane = tid & 63;
    const int r = lane & 15, q = lane >> 4;
    const int T0 = blockIdx.x * 64;
    const int bb = T0 >> 12, l0 = T0 & (L_ - 1);
    const int dw = blockIdx.y * 128 + w * 32;

    // stage y transpose: [n-major global] -> ys[t][n]
    {
        const int n = tid & 63, tg = tid >> 6;
        #pragma unroll
        for (int h2 = 0; h2 < 2; h2++) {
            uint4 v = *(const uint4*)&yH[((size_t)(bb * N_ + n)) * L_ + l0 + tg * 16 + h2 * 8];
            const f16* hh = (const f16*)&v;
            #pragma unroll
            for (int j = 0; j < 8; j++)
                ys[(tg * 16 + h2 * 8 + j) * 72 + n] = hh[j];
        }
    }
    __syncthreads();

    f32x4 acc[2][4] = {};
    #pragma unroll
    for (int ks = 0; ks < 2; ks++) {
        const int kk = ks * 32 + q * 8;
        half8 af[2];
        #pragma unroll
        for (int mf = 0; mf < 2; mf++)
            af[mf] = *(const half8*)&WoT[(size_t)(dw + mf * 16 + r) * 64 + kk];
        #pragma unroll
        for (int nf = 0; nf < 4; nf++) {
            half8 bf = *(const half8*)&ys[(nf * 16 + r) * 72 + kk];
            #pragma unroll
            for (int mf = 0; mf < 2; mf++)
                acc[mf][nf] = __builtin_amdgcn_mfma_f32_16x16x32_f16(
                    af[mf], bf, acc[mf][nf], 0, 0, 0);
        }
    }

    #pragma unroll
    for (int mf = 0; mf < 2; mf++) {
        const int d = dw + mf * 16 + q * 4;
        const float4 bb4 = *(const float4*)&bo[d];
        #pragma unroll
        for (int nf = 0; nf < 4; nf++) {
            const int t = T0 + nf * 16 + r;
            float4 o = {acc[mf][nf][0] + bb4.x, acc[mf][nf][1] + bb4.y,
                        acc[mf][nf][2] + bb4.z, acc[mf][nf][3] + bb4.w};
            *(float4*)&out[(size_t)t * D_ + d] = o;
        }
    }
}

// ---------------------------------------------------------------------------
extern "C" void kernel_launch(void* const* d_in, const int* in_sizes, int n_in,
                              void* d_out, int out_size, void* d_ws, size_t ws_size,
                              hipStream_t stream) {
    const float* x      = (const float*)d_in[0];
    const float* conv_w = (const float*)d_in[1];
    const float* conv_b = (const float*)d_in[2];
    const float* Wp     = (const float*)d_in[3];
    const float* bp     = (const float*)d_in[4];
    const float* Ws     = (const float*)d_in[5];
    const float* bs     = (const float*)d_in[6];
    const float* A_log  = (const float*)d_in[7];
    const float* dt_log = (const float*)d_in[8];
    const float* Wo     = (const float*)d_in[9];
    const float* bo     = (const float*)d_in[10];
    float* out = (float*)d_out;

    char* wsp = (char*)d_ws;
    f16* WT  = (f16*)wsp;                     // 384 KB
    f16* WoT = (f16*)(wsp + 393216);          // 128 KB
    f16* zT  = (f16*)(wsp + 524288);          // 2 MB [B,N,L]
    f16* cT  = (f16*)(wsp + 2621440);         // 2 MB
    f16* yH  = (f16*)(wsp + 4718592);         // 2 MB

    k_prepw<<<dim3(128), dim3(256), 0, stream>>>(Wp, Ws, Wo, WT, WoT);
    k_frontend<<<dim3(B_ * L_ / 32), dim3(256), 0, stream>>>(
        x, conv_w, conv_b, WT, bp, bs, dt_log, zT, cT);
    k_scan<<<dim3(B_ * N_), dim3(64), 0, stream>>>(zT, cT, A_log, dt_log, yH);
    k_out<<<dim3(B_ * L_ / 64, D_ / 128), dim3(256), 0, stream>>>(yH, WoT, bo, out);
}